// Round 8
// baseline (316.222 us; speedup 1.0000x reference)
//
#include <hip/hip_runtime.h>
#include <math.h>

#define NCLI 100
#define CPAD 112                 // clients padded to 7*16
#define DK   128                 // d-rows staged per chunk
#define NU   ((DK / 4) * 25)     // 800 staging units (4 rows x 4 cols each)
#define BUFB (CPAD * 256)        // 28672 B per buffer (112 rows x 256 B)
#define GBLK 512                 // 2 blocks/CU x 256 CU

typedef short bf16x8 __attribute__((ext_vector_type(8)));  // 8 bf16 (4 VGPRs)
typedef float f32x4  __attribute__((ext_vector_type(4)));

// Swizzled LDS byte offset for (client c, k-offset t). Row stride 256B (128 bf16)
// = 16 x 16B slots. slot = bitpairswap(c&15) ^ (c>>4).
//  - fragment reads (c&15 spans 0..15, c>>4 const): bijection -> conflict-free.
//  - staging writes (c = 4*cg+j, j fixed): cg&3 lands in slot low bits -> spread.
__device__ __forceinline__ int lds_byte(int c, int t) {
    int p = ((c >> 2) & 3) | ((c & 3) << 2);   // bit-pair swap of c&15
    int s = (p ^ (c >> 4)) & 15;
    return c * 256 + ((t * 2) ^ (s << 4));
}

// fp32 -> bf16 (RNE), bit pattern as ushort
__device__ __forceinline__ unsigned short f2bf(float x) {
    unsigned u = __float_as_uint(x);
    unsigned r = (u + 0x7fffu + ((u >> 16) & 1u)) >> 16;
    return (unsigned short)r;
}

// ---------------- tiny zero kernel (graph-safe G clear) ----------------
__global__ void zero_kernel(float4* __restrict__ p, int n4) {
    int i = blockIdx.x * blockDim.x + threadIdx.x;
    if (i < n4) p[i] = make_float4(0.f, 0.f, 0.f, 0.f);
}

// Wave W owns 16x16 output tiles: row a=W, b=W..6 (7-W tiles) and, for W>0,
// row a=7-W, b=7-W..6 (W tiles). Exactly 7 tiles per wave, A-frags {W, 7-W}.
template <int W>
__device__ __forceinline__ void compute_chunk(const char* base, f32x4 acc[7]) {
    const int lane = threadIdx.x & 63;
    const int lrow = lane & 15;        // row/col within tile
    const int kgrp = lane >> 4;        // k-group 0..3 (8 bf16 each)
    constexpr int NB = 7 - W;          // b = W..6
#pragma unroll
    for (int kk = 0; kk < DK; kk += 32) {
        const int kb = kk + kgrp * 8;
        bf16x8 bfr[NB];
#pragma unroll
        for (int j = 0; j < NB; ++j)
            bfr[j] = *(const bf16x8*)(base + lds_byte((W + j) * 16 + lrow, kb));
        bf16x8 a0 = *(const bf16x8*)(base + lds_byte(W * 16 + lrow, kb));
#pragma unroll
        for (int j = 0; j < NB; ++j)
            acc[j] = __builtin_amdgcn_mfma_f32_16x16x32_bf16(a0, bfr[j], acc[j], 0, 0, 0);
        if constexpr (W > 0) {
            bf16x8 a1 = *(const bf16x8*)(base + lds_byte((7 - W) * 16 + lrow, kb));
#pragma unroll
            for (int j = 0; j < W; ++j)
                acc[NB + j] = __builtin_amdgcn_mfma_f32_16x16x32_bf16(
                    a1, bfr[NB - W + j], acc[NB + j], 0, 0, 0);
        }
    }
}

template <int W>
__device__ __forceinline__ void store_acc(float* __restrict__ G, const f32x4 acc[7]) {
    const int lane = threadIdx.x & 63;
    const int cn = lane & 15;                 // output col within tile
    const int r0 = (lane >> 4) * 4;           // output row base within tile
#pragma unroll
    for (int j = 0; j < 7 - W; ++j) {         // tiles (W, W+j)
#pragma unroll
        for (int r = 0; r < 4; ++r) {
            int i = W * 16 + r0 + r;
            int k = (W + j) * 16 + cn;
            if (i < NCLI && k < NCLI) atomicAdd(&G[i * NCLI + k], acc[j][r]);
        }
    }
    if constexpr (W > 0) {
#pragma unroll
        for (int j = 0; j < W; ++j) {         // tiles (7-W, 7-W+j)
#pragma unroll
            for (int r = 0; r < 4; ++r) {
                int i = (7 - W) * 16 + r0 + r;
                int k = (7 - W + j) * 16 + cn;
                if (i < NCLI && k < NCLI) atomicAdd(&G[i * NCLI + k], acc[7 - W + j][r]);
            }
        }
    }
}

// ---------------- MFMA Gram, producer/consumer wave specialization ----------------
// 512 threads: waves 0-3 = consumers (MFMA), waves 4-7 = producers (load+convert+
// ds_write). Two LDS buffers, ONE __syncthreads per chunk:
//   iter e: { producers stage chunk e -> buf[e&1]  ||  consumers compute chunk e-1
//             from buf[(e-1)&1] }  then barrier.
// Race-free: stage(e+1) overwrites buf[(e+1)&1] = the buffer consumers read at
// iter e, separated by the end-of-e barrier; __syncthreads drains ds ops; each
// producer's loads complete before its own ds_writes (register dependency).
// While producers stall on HBM latency, consumer waves keep the SIMDs busy --
// this removes the all-waves-stalled staging phase (r6: VALUBusy 6%, occ 13%).
__global__ __launch_bounds__(512, 4) void gram_mfma(const float* __restrict__ A,
                                                    float* __restrict__ G,
                                                    long dtot, int nchunks) {
    __shared__ uint4 ldsq[2 * BUFB / 16];   // 57344 B -> 2 blocks/CU
    char* base = (char*)ldsq;
    const int tid = threadIdx.x;
    const int wid = tid >> 6;               // 0..7
    const bool producer = (wid >= 4);
    const int ptid = tid & 255;             // producer-local id 0..255

    // zero pad-client rows 100..111 in BOTH buffers (whole rows zero)
    for (int u = tid; u < 2 * (CPAD - NCLI) * 64; u += 512) {
        int b = u >> 10;                    // (CPAD-NCLI)*64 = 768; use /768
        b = u / ((CPAD - NCLI) * 64);
        int o = u - b * ((CPAD - NCLI) * 64);
        ((unsigned*)(base + b * BUFB + NCLI * 256))[o] = 0u;
    }

    f32x4 acc[7];
#pragma unroll
    for (int q = 0; q < 7; ++q) acc[q] = (f32x4)(0.0f);

    int nb = 0;
    if ((int)blockIdx.x < nchunks)
        nb = (nchunks - 1 - (int)blockIdx.x) / (int)gridDim.x + 1;

    for (int e = 0; e <= nb; ++e) {
        if (producer && e < nb) {
            char* bb = base + (e & 1) * BUFB;
            const long d0 = ((long)blockIdx.x + (long)e * gridDim.x) * DK;
            // phase A: issue all loads (producers have no other work; latency
            // overlaps consumer MFMA on the same CU)
            float4 v[4][4];
#pragma unroll
            for (int s = 0; s < 4; ++s) {
                if (s < 3 || ptid < NU - 768) {
                    const int u = ptid + s * 256;
                    const int rg = u / 25;            // 4-row group 0..31
                    const int cg = u - rg * 25;       // 4-col group 0..24
#pragma unroll
                    for (int r = 0; r < 4; ++r) {
                        const long dr = d0 + rg * 4 + r;
                        v[s][r] = (dr < dtot)
                                      ? *(const float4*)(A + dr * NCLI + cg * 4)
                                      : make_float4(0.f, 0.f, 0.f, 0.f);
                    }
                }
            }
            // phase B: convert fp32->bf16, write transposed into LDS
#pragma unroll
            for (int s = 0; s < 4; ++s) {
                if (s < 3 || ptid < NU - 768) {
                    const int u = ptid + s * 256;
                    const int rg = u / 25;
                    const int cg = u - rg * 25;
#pragma unroll
                    for (int j = 0; j < 4; ++j) {
                        const int c = cg * 4 + j;
                        ushort4 p;
                        p.x = f2bf(((const float*)&v[s][0])[j]);
                        p.y = f2bf(((const float*)&v[s][1])[j]);
                        p.z = f2bf(((const float*)&v[s][2])[j]);
                        p.w = f2bf(((const float*)&v[s][3])[j]);
                        *(ushort4*)(bb + lds_byte(c, rg * 4)) = p;
                    }
                }
            }
        } else if (!producer && e > 0) {
            const char* bb = base + ((e - 1) & 1) * BUFB;
            if (wid == 0)      compute_chunk<0>(bb, acc);
            else if (wid == 1) compute_chunk<1>(bb, acc);
            else if (wid == 2) compute_chunk<2>(bb, acc);
            else               compute_chunk<3>(bb, acc);
        }
        __syncthreads();
    }

    if (wid == 0)      store_acc<0>(G, acc);
    else if (wid == 1) store_acc<1>(G, acc);
    else if (wid == 2) store_acc<2>(G, acc);
    else if (wid == 3) store_acc<3>(G, acc);
}

// ---------------- Weights kernel: full FoolsGold weight computation, single block ----------------
__global__ __launch_bounds__(128) void weights_kernel(const float* __restrict__ G,
                                                      float* __restrict__ w) {
    __shared__ float cs[NCLI][NCLI + 1];
    __shared__ float nrm[NCLI], maxcs[NCLI], wv[NCLI];
    __shared__ float red[2];
    const int t = threadIdx.x;

    if (t < NCLI) {
        float g = G[t * NCLI + t];
        nrm[t] = fmaxf(sqrtf(g), 1e-12f);
    }
    __syncthreads();

    for (int idx = t; idx < NCLI * NCLI; idx += 128) {
        int i = idx / NCLI;
        int j = idx - i * NCLI;
        int a = i < j ? i : j;
        int b = i < j ? j : i;
        float c = G[a * NCLI + b] / (nrm[i] * nrm[j]);
        if (i == j) c -= 1.0f;
        cs[i][j] = c;
    }
    __syncthreads();

    if (t < NCLI) {
        float m = -1e30f;
        for (int j = 0; j < NCLI; ++j) m = fmaxf(m, cs[t][j]);
        maxcs[t] = m;
    }
    __syncthreads();

    if (t < NCLI) {
        float mi = maxcs[t];
        float m = -1e30f;
        for (int j = 0; j < NCLI; ++j) {
            float v = cs[t][j];
            float mj = maxcs[j];
            if (t != j && mi < mj) v *= mi / mj;  // pardoning
            m = fmaxf(m, v);
        }
        float x = 1.0f - m;
        x = fminf(fmaxf(x, 0.0f), 1.0f);
        wv[t] = x;
    }
    __syncthreads();

    if (t == 0) {
        float m = 0.0f;
        for (int i = 0; i < NCLI; ++i) m = fmaxf(m, wv[i]);
        red[0] = m;
    }
    __syncthreads();

    if (t < NCLI) {
        float x = wv[t] / red[0];
        if (x == 1.0f) x = 0.99f;
        float l = logf(x / (1.0f - x)) + 0.5f;
        float flag = isinf(l) ? 1.0f : 0.0f;   // torch: wv[isinf(wv)+wv > 1] = 1
        l = (flag + l > 1.0f) ? 1.0f : l;
        l = (l < 0.0f) ? 0.0f : l;
        wv[t] = l;
    }
    __syncthreads();

    if (t == 0) {
        float s = 0.0f;
        for (int i = 0; i < NCLI; ++i) s += wv[i];
        red[1] = s;
    }
    __syncthreads();

    if (t < NCLI) w[t] = wv[t] / red[1];
}

// ---------------- Output kernel: out[j] = dot(A[j][:], w) ----------------
// Direct per-lane-row float4 loads (high TLP). Tail-first block->row mapping:
// gram streamed A head->tail, so L3 holds A's tail at gram-end.
__global__ __launch_bounds__(256) void out_kernel(const float* __restrict__ A,
                                                  const float* __restrict__ w,
                                                  float* __restrict__ out, int d,
                                                  int nblocks) {
    __shared__ float4 w4[NCLI / 4];
    if (threadIdx.x < NCLI / 4) w4[threadIdx.x] = ((const float4*)w)[threadIdx.x];
    __syncthreads();
    const long rb = (long)(nblocks - 1 - blockIdx.x) * 256;  // tail-first
    const long j = rb + threadIdx.x;
    if (j >= d) return;
    const float4* row = (const float4*)(A + j * NCLI);  // 400B rows, 16B aligned
    float s0 = 0.0f, s1 = 0.0f;
#pragma unroll
    for (int q = 0; q < NCLI / 8; ++q) {   // 12 pairs
        float4 v0 = row[2 * q];
        float4 ww0 = w4[2 * q];
        float4 v1 = row[2 * q + 1];
        float4 ww1 = w4[2 * q + 1];
        s0 += v0.x * ww0.x + v0.y * ww0.y + v0.z * ww0.z + v0.w * ww0.w;
        s1 += v1.x * ww1.x + v1.y * ww1.y + v1.z * ww1.z + v1.w * ww1.w;
    }
    {
        float4 v = row[24];
        float4 ww = w4[24];
        s0 += v.x * ww.x + v.y * ww.y + v.z * ww.z + v.w * ww.w;
    }
    out[j] = s0 + s1;
}

extern "C" void kernel_launch(void* const* d_in, const int* in_sizes, int n_in,
                              void* d_out, int out_size, void* d_ws, size_t ws_size,
                              hipStream_t stream) {
    const float* A = (const float*)d_in[0];
    float* out = (float*)d_out;
    const int d = in_sizes[0] / NCLI;

    float* G = (float*)d_ws;           // 100*100 f32 (upper triangle used)
    float* w = G + NCLI * NCLI;        // 100 f32 weights

    const int n4 = (NCLI * NCLI) / 4;  // 2500 float4
    zero_kernel<<<(n4 + 255) / 256, 256, 0, stream>>>((float4*)G, n4);

    const int nchunks = (d + DK - 1) / DK;
    const int gblocks = nchunks < GBLK ? nchunks : GBLK;
    gram_mfma<<<gblocks, 512, 0, stream>>>(A, G, (long)d, nchunks);

    weights_kernel<<<1, 128, 0, stream>>>(G, w);

    const int oblocks = (d + 255) / 256;
    out_kernel<<<oblocks, 256, 0, stream>>>(A, w, out, d, oblocks);
}

// Round 9
// 240.683 us; speedup vs baseline: 1.3139x; 1.3139x over previous
//
#include <hip/hip_runtime.h>
#include <math.h>

#define NCLI 100
#define CPAD 112                  // clients padded to 7*16
#define DK   64                   // d-rows per chunk
#define RAWB 28672                // raw fp32 buffer bytes (1792 float4, padded from 1600)
#define BFB  (CPAD * DK * 2)      // 14336 B bf16 transposed buffer
#define GBLK 512                  // 2 blocks/CU x 256 CU

typedef short bf16x8 __attribute__((ext_vector_type(8)));  // 8 bf16 (4 VGPRs)
typedef float f32x4  __attribute__((ext_vector_type(4)));

// bf16 buffer byte offset for (client c, k-offset t). Row stride 128B = 8 x 16B
// slots. slot = (c&7) ^ ((c>>3)&7):
//  - fragment reads: 16 consecutive c -> each 8-slot set twice -> 2 lanes/slot
//    across the wave = 2-way = free (m136).
//  - staging writes: c=4cg+j spreads via cg bits -> ~4-way worst, minor.
__device__ __forceinline__ int bf_byte(int c, int t) {
    int s = (c & 7) ^ ((c >> 3) & 7);
    return c * 128 + ((t * 2) ^ (s << 4));
}

// fp32 -> bf16 (RNE), bit pattern as ushort
__device__ __forceinline__ unsigned short f2bf(float x) {
    unsigned u = __float_as_uint(x);
    unsigned r = (u + 0x7fffu + ((u >> 16) & 1u)) >> 16;
    return (unsigned short)r;
}

// ---------------- tiny zero kernel (graph-safe G clear) ----------------
__global__ void zero_kernel(float4* __restrict__ p, int n4) {
    int i = blockIdx.x * blockDim.x + threadIdx.x;
    if (i < n4) p[i] = make_float4(0.f, 0.f, 0.f, 0.f);
}

// ---- async DMA: chunk (64 rows x 400B, CONTIGUOUS in A) -> linear LDS raw ----
// 7 uniform global_load_lds(16B) per thread; per-lane global addr clamped so all
// waves issue exactly 7 (uniform vmcnt); LDS dest = wave-uniform base + lane*16
// (HW rule, m104) -> linear layout matching A. No VGPR data path -> nothing to
// spill, nothing alive across barriers.
__device__ __forceinline__ void stage_issue(const float* __restrict__ A, long c0,
                                            char* raw, int tid, long dtot) {
    const long gword0 = c0 * (DK * NCLI);
    const long gmax = dtot * NCLI - 4;       // last safe float4 word start
    const int wbyte = (tid & ~63) << 4;      // wave-uniform byte base
#pragma unroll
    for (int i = 0; i < 7; ++i) {
        int f = i * 256 + tid;
        if (f > 1599) f = 1599;              // pad issues re-load last float4
        long gw = gword0 + (long)f * 4;
        if (gw > gmax) gw = gmax;
        __builtin_amdgcn_global_load_lds(
            (const __attribute__((address_space(1))) unsigned*)(A + gw),
            (__attribute__((address_space(3))) unsigned*)(raw + i * 4096 + wbyte),
            16, 0, 0);
    }
}

// ---- LDS->LDS transpose + fp32->bf16 convert (raw linear -> bf swizzled) ----
__device__ __forceinline__ void transpose_convert(const char* raw, char* bf,
                                                  int tid, long d0, long dtot) {
#pragma unroll
    for (int s = 0; s < 2; ++s) {
        if (s == 0 || tid < 144) {           // units u < 400
            const int u = tid + s * 256;
            const int rg = u / 25;           // 4-row group 0..15
            const int cg = u - rg * 25;      // 4-col group 0..24
            float4 v[4];
#pragma unroll
            for (int r = 0; r < 4; ++r) {
                v[r] = *(const float4*)(raw + (((rg * 4 + r) * 25 + cg) << 4));
                if (d0 + rg * 4 + r >= dtot) v[r] = make_float4(0.f, 0.f, 0.f, 0.f);
            }
#pragma unroll
            for (int j = 0; j < 4; ++j) {
                const int c = cg * 4 + j;
                ushort4 p;
                p.x = f2bf(((const float*)&v[0])[j]);
                p.y = f2bf(((const float*)&v[1])[j]);
                p.z = f2bf(((const float*)&v[2])[j]);
                p.w = f2bf(((const float*)&v[3])[j]);
                *(ushort4*)(bf + bf_byte(c, rg * 4)) = p;   // 8B, 8B-aligned
            }
        }
    }
}

// Wave W owns 16x16 output tiles: row a=W, b=W..6 (7-W tiles) and, for W>0,
// row a=7-W, b=7-W..6 (W tiles). Exactly 7 tiles per wave, A-frags {W, 7-W}.
template <int W>
__device__ __forceinline__ void compute_chunk(const char* bf, f32x4 acc[7]) {
    const int lane = threadIdx.x & 63;
    const int lrow = lane & 15;        // row/col within tile
    const int kgrp = lane >> 4;        // k-group 0..3 (8 bf16 each)
    constexpr int NB = 7 - W;          // b = W..6
#pragma unroll
    for (int kk = 0; kk < DK; kk += 32) {
        const int kb = kk + kgrp * 8;
        bf16x8 bfr[NB];
#pragma unroll
        for (int j = 0; j < NB; ++j)
            bfr[j] = *(const bf16x8*)(bf + bf_byte((W + j) * 16 + lrow, kb));
        bf16x8 a0 = *(const bf16x8*)(bf + bf_byte(W * 16 + lrow, kb));
#pragma unroll
        for (int j = 0; j < NB; ++j)
            acc[j] = __builtin_amdgcn_mfma_f32_16x16x32_bf16(a0, bfr[j], acc[j], 0, 0, 0);
        if constexpr (W > 0) {
            bf16x8 a1 = *(const bf16x8*)(bf + bf_byte((7 - W) * 16 + lrow, kb));
#pragma unroll
            for (int j = 0; j < W; ++j)
                acc[NB + j] = __builtin_amdgcn_mfma_f32_16x16x32_bf16(
                    a1, bfr[NB - W + j], acc[NB + j], 0, 0, 0);
        }
    }
}

template <int W>
__device__ __forceinline__ void store_acc(float* __restrict__ G, const f32x4 acc[7]) {
    const int lane = threadIdx.x & 63;
    const int cn = lane & 15;                 // output col within tile
    const int r0 = (lane >> 4) * 4;           // output row base within tile
#pragma unroll
    for (int j = 0; j < 7 - W; ++j) {         // tiles (W, W+j)
#pragma unroll
        for (int r = 0; r < 4; ++r) {
            int i = W * 16 + r0 + r;
            int k = (W + j) * 16 + cn;
            if (i < NCLI && k < NCLI) atomicAdd(&G[i * NCLI + k], acc[j][r]);
        }
    }
    if constexpr (W > 0) {
#pragma unroll
        for (int j = 0; j < W; ++j) {         // tiles (7-W, 7-W+j)
#pragma unroll
            for (int r = 0; r < 4; ++r) {
                int i = (7 - W) * 16 + r0 + r;
                int k = (7 - W + j) * 16 + cn;
                if (i < NCLI && k < NCLI) atomicAdd(&G[i * NCLI + k], acc[7 - W + j][r]);
            }
        }
    }
}

// ---------------- MFMA Gram, async-DMA pipelined (T3/T4 analog) ----------------
// Per chunk e: { issue DMA chunk e+1 -> raw[(e+1)&1] | s_waitcnt vmcnt(7)
// (drain chunk e only; e+1 stays in flight) | s_barrier | transpose raw[e&1]
// -> bf | lgkmcnt(0)+s_barrier | MFMA from bf }.
// Buffer safety: DMA into raw[(e+1)&1] reuses the buffer transpose read at
// iter e-1, separated by this iter's first barrier; bf single-buffered (write
// and read separated by the second barrier; next write at e+1 separated from
// this read by e+1's first barrier -- reads are consumed by MFMAs before the
// wave arrives there). vmcnt counts are uniform (7 issues always) and FIFO.
__global__ __launch_bounds__(256, 2) void gram_mfma(const float* __restrict__ A,
                                                    float* __restrict__ G,
                                                    long dtot, int nchunks) {
    __shared__ char lds[2 * RAWB + BFB];   // 71680 B -> 2 blocks/CU
    char* bf = lds + 2 * RAWB;
    const int tid = threadIdx.x;
    const int wid = tid >> 6;

    // zero bf pad-client rows 100..111 once (whole rows zero, swizzle-internal)
    for (int u = tid; u < (CPAD - NCLI) * 32; u += 256)
        ((unsigned*)(bf + NCLI * 128))[u] = 0u;
    __syncthreads();

    f32x4 acc[7];
#pragma unroll
    for (int q = 0; q < 7; ++q) acc[q] = (f32x4)(0.0f);

    int nb = 0;
    if ((int)blockIdx.x < nchunks)
        nb = (nchunks - 1 - (int)blockIdx.x) / (int)gridDim.x + 1;

    if (nb > 0)
        stage_issue(A, (long)blockIdx.x, lds, tid, dtot);   // prologue -> raw0

    for (int e = 0; e < nb; ++e) {
        char* raw_cur = lds + (e & 1) * RAWB;
        if (e + 1 < nb) {
            stage_issue(A, (long)blockIdx.x + (long)(e + 1) * gridDim.x,
                        lds + ((e + 1) & 1) * RAWB, tid, dtot);
            asm volatile("s_waitcnt vmcnt(7)" ::: "memory");   // drain chunk e
        } else {
            asm volatile("s_waitcnt vmcnt(0)" ::: "memory");
        }
        __builtin_amdgcn_s_barrier();
        asm volatile("" ::: "memory");

        transpose_convert(raw_cur, bf, tid,
                          ((long)blockIdx.x + (long)e * gridDim.x) * DK, dtot);

        asm volatile("s_waitcnt lgkmcnt(0)" ::: "memory");
        __builtin_amdgcn_s_barrier();
        asm volatile("" ::: "memory");

        if (wid == 0)      compute_chunk<0>(bf, acc);
        else if (wid == 1) compute_chunk<1>(bf, acc);
        else if (wid == 2) compute_chunk<2>(bf, acc);
        else               compute_chunk<3>(bf, acc);
    }

    if (wid == 0)      store_acc<0>(G, acc);
    else if (wid == 1) store_acc<1>(G, acc);
    else if (wid == 2) store_acc<2>(G, acc);
    else               store_acc<3>(G, acc);
}

// ---------------- Weights kernel: full FoolsGold weight computation, single block ----------------
__global__ __launch_bounds__(128) void weights_kernel(const float* __restrict__ G,
                                                      float* __restrict__ w) {
    __shared__ float cs[NCLI][NCLI + 1];
    __shared__ float nrm[NCLI], maxcs[NCLI], wv[NCLI];
    __shared__ float red[2];
    const int t = threadIdx.x;

    if (t < NCLI) {
        float g = G[t * NCLI + t];
        nrm[t] = fmaxf(sqrtf(g), 1e-12f);
    }
    __syncthreads();

    for (int idx = t; idx < NCLI * NCLI; idx += 128) {
        int i = idx / NCLI;
        int j = idx - i * NCLI;
        int a = i < j ? i : j;
        int b = i < j ? j : i;
        float c = G[a * NCLI + b] / (nrm[i] * nrm[j]);
        if (i == j) c -= 1.0f;
        cs[i][j] = c;
    }
    __syncthreads();

    if (t < NCLI) {
        float m = -1e30f;
        for (int j = 0; j < NCLI; ++j) m = fmaxf(m, cs[t][j]);
        maxcs[t] = m;
    }
    __syncthreads();

    if (t < NCLI) {
        float mi = maxcs[t];
        float m = -1e30f;
        for (int j = 0; j < NCLI; ++j) {
            float v = cs[t][j];
            float mj = maxcs[j];
            if (t != j && mi < mj) v *= mi / mj;  // pardoning
            m = fmaxf(m, v);
        }
        float x = 1.0f - m;
        x = fminf(fmaxf(x, 0.0f), 1.0f);
        wv[t] = x;
    }
    __syncthreads();

    if (t == 0) {
        float m = 0.0f;
        for (int i = 0; i < NCLI; ++i) m = fmaxf(m, wv[i]);
        red[0] = m;
    }
    __syncthreads();

    if (t < NCLI) {
        float x = wv[t] / red[0];
        if (x == 1.0f) x = 0.99f;
        float l = logf(x / (1.0f - x)) + 0.5f;
        float flag = isinf(l) ? 1.0f : 0.0f;   // torch: wv[isinf(wv)+wv > 1] = 1
        l = (flag + l > 1.0f) ? 1.0f : l;
        l = (l < 0.0f) ? 0.0f : l;
        wv[t] = l;
    }
    __syncthreads();

    if (t == 0) {
        float s = 0.0f;
        for (int i = 0; i < NCLI; ++i) s += wv[i];
        red[1] = s;
    }
    __syncthreads();

    if (t < NCLI) w[t] = wv[t] / red[1];
}

// ---------------- Output kernel: out[j] = dot(A[j][:], w) ----------------
// Direct per-lane-row float4 loads (high TLP). Tail-first block->row mapping:
// gram streamed A head->tail, so L3 holds A's tail at gram-end.
__global__ __launch_bounds__(256) void out_kernel(const float* __restrict__ A,
                                                  const float* __restrict__ w,
                                                  float* __restrict__ out, int d,
                                                  int nblocks) {
    __shared__ float4 w4[NCLI / 4];
    if (threadIdx.x < NCLI / 4) w4[threadIdx.x] = ((const float4*)w)[threadIdx.x];
    __syncthreads();
    const long rb = (long)(nblocks - 1 - blockIdx.x) * 256;  // tail-first
    const long j = rb + threadIdx.x;
    if (j >= d) return;
    const float4* row = (const float4*)(A + j * NCLI);  // 400B rows, 16B aligned
    float s0 = 0.0f, s1 = 0.0f;
#pragma unroll
    for (int q = 0; q < NCLI / 8; ++q) {   // 12 pairs
        float4 v0 = row[2 * q];
        float4 ww0 = w4[2 * q];
        float4 v1 = row[2 * q + 1];
        float4 ww1 = w4[2 * q + 1];
        s0 += v0.x * ww0.x + v0.y * ww0.y + v0.z * ww0.z + v0.w * ww0.w;
        s1 += v1.x * ww1.x + v1.y * ww1.y + v1.z * ww1.z + v1.w * ww1.w;
    }
    {
        float4 v = row[24];
        float4 ww = w4[24];
        s0 += v.x * ww.x + v.y * ww.y + v.z * ww.z + v.w * ww.w;
    }
    out[j] = s0 + s1;
}

extern "C" void kernel_launch(void* const* d_in, const int* in_sizes, int n_in,
                              void* d_out, int out_size, void* d_ws, size_t ws_size,
                              hipStream_t stream) {
    const float* A = (const float*)d_in[0];
    float* out = (float*)d_out;
    const int d = in_sizes[0] / NCLI;

    float* G = (float*)d_ws;           // 100*100 f32 (upper triangle used)
    float* w = G + NCLI * NCLI;        // 100 f32 weights

    const int n4 = (NCLI * NCLI) / 4;  // 2500 float4
    zero_kernel<<<(n4 + 255) / 256, 256, 0, stream>>>((float4*)G, n4);

    const int nchunks = (d + DK - 1) / DK;
    const int gblocks = nchunks < GBLK ? nchunks : GBLK;
    gram_mfma<<<gblocks, 256, 0, stream>>>(A, G, (long)d, nchunks);

    weights_kernel<<<1, 128, 0, stream>>>(G, w);

    const int oblocks = (d + 255) / 256;
    out_kernel<<<oblocks, 256, 0, stream>>>(A, w, out, d, oblocks);
}

// Round 10
// 200.836 us; speedup vs baseline: 1.5745x; 1.1984x over previous
//
#include <hip/hip_runtime.h>
#include <math.h>

#define NCLI 100
#define CPAD 112                  // clients padded to 7*16
#define DK   64                   // d-rows per chunk
#define RAWB 28672                // raw fp32 buffer bytes (1792 float4, padded from 1600)
#define BFB  (CPAD * DK * 2)      // 14336 B bf16 transposed buffer
#define GBLK 512                  // 2 blocks/CU x 256 CU

typedef short bf16x8 __attribute__((ext_vector_type(8)));  // 8 bf16 (4 VGPRs)
typedef float f32x4  __attribute__((ext_vector_type(4)));

// bf16 buffer byte offset for (client c, k-offset t). Row stride 128B = 8 x 16B
// slots. slot = (c&7) ^ ((c>>3)&7).
__device__ __forceinline__ int bf_byte(int c, int t) {
    int s = (c & 7) ^ ((c >> 3) & 7);
    return c * 128 + ((t * 2) ^ (s << 4));
}

// fp32 -> bf16 (RNE), bit pattern as ushort
__device__ __forceinline__ unsigned short f2bf(float x) {
    unsigned u = __float_as_uint(x);
    unsigned r = (u + 0x7fffu + ((u >> 16) & 1u)) >> 16;
    return (unsigned short)r;
}

// ---------------- tiny zero kernel (graph-safe G clear) ----------------
__global__ void zero_kernel(float4* __restrict__ p, int n4) {
    int i = blockIdx.x * blockDim.x + threadIdx.x;
    if (i < n4) p[i] = make_float4(0.f, 0.f, 0.f, 0.f);
}

// ---- async DMA: chunk (64 rows x 400B, CONTIGUOUS in A) -> linear LDS raw ----
__device__ __forceinline__ void stage_issue(const float* __restrict__ A, long c0,
                                            char* raw, int tid, long dtot) {
    const long gword0 = c0 * (DK * NCLI);
    const long gmax = dtot * NCLI - 4;       // last safe float4 word start
    const int wbyte = (tid & ~63) << 4;      // wave-uniform byte base
#pragma unroll
    for (int i = 0; i < 7; ++i) {
        int f = i * 256 + tid;
        if (f > 1599) f = 1599;              // pad issues re-load last float4
        long gw = gword0 + (long)f * 4;
        if (gw > gmax) gw = gmax;
        __builtin_amdgcn_global_load_lds(
            (const __attribute__((address_space(1))) unsigned*)(A + gw),
            (__attribute__((address_space(3))) unsigned*)(raw + i * 4096 + wbyte),
            16, 0, 0);
    }
}

// ---- LDS->LDS transpose + fp32->bf16 convert (raw linear -> bf swizzled) ----
__device__ __forceinline__ void transpose_convert(const char* raw, char* bf,
                                                  int tid, long d0, long dtot) {
#pragma unroll
    for (int s = 0; s < 2; ++s) {
        if (s == 0 || tid < 144) {           // units u < 400
            const int u = tid + s * 256;
            const int rg = u / 25;           // 4-row group 0..15
            const int cg = u - rg * 25;      // 4-col group 0..24
            float4 v[4];
#pragma unroll
            for (int r = 0; r < 4; ++r) {
                v[r] = *(const float4*)(raw + (((rg * 4 + r) * 25 + cg) << 4));
                if (d0 + rg * 4 + r >= dtot) v[r] = make_float4(0.f, 0.f, 0.f, 0.f);
            }
#pragma unroll
            for (int j = 0; j < 4; ++j) {
                const int c = cg * 4 + j;
                ushort4 p;
                p.x = f2bf(((const float*)&v[0])[j]);
                p.y = f2bf(((const float*)&v[1])[j]);
                p.z = f2bf(((const float*)&v[2])[j]);
                p.w = f2bf(((const float*)&v[3])[j]);
                *(ushort4*)(bf + bf_byte(c, rg * 4)) = p;   // 8B, 8B-aligned
            }
        }
    }
}

// Wave W owns 16x16 output tiles: row a=W, b=W..6 (7-W tiles) and, for W>0,
// row a=7-W, b=7-W..6 (W tiles). Exactly 7 tiles per wave, A-frags {W, 7-W}.
template <int W>
__device__ __forceinline__ void compute_chunk(const char* bf, f32x4 acc[7]) {
    const int lane = threadIdx.x & 63;
    const int lrow = lane & 15;        // row/col within tile
    const int kgrp = lane >> 4;        // k-group 0..3 (8 bf16 each)
    constexpr int NB = 7 - W;          // b = W..6
#pragma unroll
    for (int kk = 0; kk < DK; kk += 32) {
        const int kb = kk + kgrp * 8;
        bf16x8 bfr[NB];
#pragma unroll
        for (int j = 0; j < NB; ++j)
            bfr[j] = *(const bf16x8*)(bf + bf_byte((W + j) * 16 + lrow, kb));
        bf16x8 a0 = *(const bf16x8*)(bf + bf_byte(W * 16 + lrow, kb));
#pragma unroll
        for (int j = 0; j < NB; ++j)
            acc[j] = __builtin_amdgcn_mfma_f32_16x16x32_bf16(a0, bfr[j], acc[j], 0, 0, 0);
        if constexpr (W > 0) {
            bf16x8 a1 = *(const bf16x8*)(bf + bf_byte((7 - W) * 16 + lrow, kb));
#pragma unroll
            for (int j = 0; j < W; ++j)
                acc[NB + j] = __builtin_amdgcn_mfma_f32_16x16x32_bf16(
                    a1, bfr[NB - W + j], acc[NB + j], 0, 0, 0);
        }
    }
}

template <int W>
__device__ __forceinline__ void store_acc(float* __restrict__ G, const f32x4 acc[7]) {
    const int lane = threadIdx.x & 63;
    const int cn = lane & 15;                 // output col within tile
    const int r0 = (lane >> 4) * 4;           // output row base within tile
#pragma unroll
    for (int j = 0; j < 7 - W; ++j) {         // tiles (W, W+j)
#pragma unroll
        for (int r = 0; r < 4; ++r) {
            int i = W * 16 + r0 + r;
            int k = (W + j) * 16 + cn;
            if (i < NCLI && k < NCLI) atomicAdd(&G[i * NCLI + k], acc[j][r]);
        }
    }
    if constexpr (W > 0) {
#pragma unroll
        for (int j = 0; j < W; ++j) {         // tiles (7-W, 7-W+j)
#pragma unroll
            for (int r = 0; r < 4; ++r) {
                int i = (7 - W) * 16 + r0 + r;
                int k = (7 - W + j) * 16 + cn;
                if (i < NCLI && k < NCLI) atomicAdd(&G[i * NCLI + k], acc[7 - W + j][r]);
            }
        }
    }
}

// ---------------- MFMA Gram, async-DMA pipelined (unchanged from r9) ----------------
__global__ __launch_bounds__(256, 2) void gram_mfma(const float* __restrict__ A,
                                                    float* __restrict__ G,
                                                    long dtot, int nchunks) {
    __shared__ char lds[2 * RAWB + BFB];   // 71680 B -> 2 blocks/CU
    char* bf = lds + 2 * RAWB;
    const int tid = threadIdx.x;
    const int wid = tid >> 6;

    // zero bf pad-client rows 100..111 once (whole rows zero, swizzle-internal)
    for (int u = tid; u < (CPAD - NCLI) * 32; u += 256)
        ((unsigned*)(bf + NCLI * 128))[u] = 0u;
    __syncthreads();

    f32x4 acc[7];
#pragma unroll
    for (int q = 0; q < 7; ++q) acc[q] = (f32x4)(0.0f);

    int nb = 0;
    if ((int)blockIdx.x < nchunks)
        nb = (nchunks - 1 - (int)blockIdx.x) / (int)gridDim.x + 1;

    if (nb > 0)
        stage_issue(A, (long)blockIdx.x, lds, tid, dtot);   // prologue -> raw0

    for (int e = 0; e < nb; ++e) {
        char* raw_cur = lds + (e & 1) * RAWB;
        if (e + 1 < nb) {
            stage_issue(A, (long)blockIdx.x + (long)(e + 1) * gridDim.x,
                        lds + ((e + 1) & 1) * RAWB, tid, dtot);
            asm volatile("s_waitcnt vmcnt(7)" ::: "memory");   // drain chunk e
        } else {
            asm volatile("s_waitcnt vmcnt(0)" ::: "memory");
        }
        __builtin_amdgcn_s_barrier();
        asm volatile("" ::: "memory");

        transpose_convert(raw_cur, bf, tid,
                          ((long)blockIdx.x + (long)e * gridDim.x) * DK, dtot);

        asm volatile("s_waitcnt lgkmcnt(0)" ::: "memory");
        __builtin_amdgcn_s_barrier();
        asm volatile("" ::: "memory");

        if (wid == 0)      compute_chunk<0>(bf, acc);
        else if (wid == 1) compute_chunk<1>(bf, acc);
        else if (wid == 2) compute_chunk<2>(bf, acc);
        else               compute_chunk<3>(bf, acc);
    }

    if (wid == 0)      store_acc<0>(G, acc);
    else if (wid == 1) store_acc<1>(G, acc);
    else if (wid == 2) store_acc<2>(G, acc);
    else               store_acc<3>(G, acc);
}

// ---------------- Weights kernel: full FoolsGold weight computation, single block ----------------
__global__ __launch_bounds__(128) void weights_kernel(const float* __restrict__ G,
                                                      float* __restrict__ w) {
    __shared__ float cs[NCLI][NCLI + 1];
    __shared__ float nrm[NCLI], maxcs[NCLI], wv[NCLI];
    __shared__ float red[2];
    const int t = threadIdx.x;

    if (t < NCLI) {
        float g = G[t * NCLI + t];
        nrm[t] = fmaxf(sqrtf(g), 1e-12f);
    }
    __syncthreads();

    for (int idx = t; idx < NCLI * NCLI; idx += 128) {
        int i = idx / NCLI;
        int j = idx - i * NCLI;
        int a = i < j ? i : j;
        int b = i < j ? j : i;
        float c = G[a * NCLI + b] / (nrm[i] * nrm[j]);
        if (i == j) c -= 1.0f;
        cs[i][j] = c;
    }
    __syncthreads();

    if (t < NCLI) {
        float m = -1e30f;
        for (int j = 0; j < NCLI; ++j) m = fmaxf(m, cs[t][j]);
        maxcs[t] = m;
    }
    __syncthreads();

    if (t < NCLI) {
        float mi = maxcs[t];
        float m = -1e30f;
        for (int j = 0; j < NCLI; ++j) {
            float v = cs[t][j];
            float mj = maxcs[j];
            if (t != j && mi < mj) v *= mi / mj;  // pardoning
            m = fmaxf(m, v);
        }
        float x = 1.0f - m;
        x = fminf(fmaxf(x, 0.0f), 1.0f);
        wv[t] = x;
    }
    __syncthreads();

    if (t == 0) {
        float m = 0.0f;
        for (int i = 0; i < NCLI; ++i) m = fmaxf(m, wv[i]);
        red[0] = m;
    }
    __syncthreads();

    if (t < NCLI) {
        float x = wv[t] / red[0];
        if (x == 1.0f) x = 0.99f;
        float l = logf(x / (1.0f - x)) + 0.5f;
        float flag = isinf(l) ? 1.0f : 0.0f;   // torch: wv[isinf(wv)+wv > 1] = 1
        l = (flag + l > 1.0f) ? 1.0f : l;
        l = (l < 0.0f) ? 0.0f : l;
        wv[t] = l;
    }
    __syncthreads();

    if (t == 0) {
        float s = 0.0f;
        for (int i = 0; i < NCLI; ++i) s += wv[i];
        red[1] = s;
    }
    __syncthreads();

    if (t < NCLI) w[t] = wv[t] / red[1];
}

// ---------------- Output kernel: out[j] = dot(A[j][:], w), quarter-row ----------------
// 4 lanes per row (q = (lane&3) + 4k): per instruction the wave touches 16 rows
// x 64B contiguous segments (16 cache lines, 4x fewer than per-lane-row), and a
// row's 3.1 lines are consumed within one 6-load window -> L1 footprint per
// wave window 6.4KB (was 25.6KB) -> kills the L1-thrash re-fetch from L2.
// No LDS staging / barriers (T14-null regime: streaming op at high occupancy).
// Reduction: 2 shfl_xor over the 4-lane group; q=24 tail done by quarter q0==0.
// Tail-first block->row mapping preserves gram's L3 tail residency.
__global__ __launch_bounds__(256) void out_kernel(const float* __restrict__ A,
                                                  const float* __restrict__ w,
                                                  float* __restrict__ out, int d,
                                                  int nblocks) {
    __shared__ float4 w4s[NCLI / 4];
    if (threadIdx.x < NCLI / 4) w4s[threadIdx.x] = ((const float4*)w)[threadIdx.x];
    __syncthreads();

    const int lane = threadIdx.x & 63;
    const int wid = threadIdx.x >> 6;
    const int q0 = lane & 3;                  // quarter id 0..3
    const int rsub = lane >> 2;               // row-within-wave 0..15

    const long rb = (long)(nblocks - 1 - blockIdx.x) * 64;   // 64 rows/block, tail-first
    const long row = rb + wid * 16 + rsub;
    if (row >= d) return;

    const float4* r4 = (const float4*)(A + row * NCLI);
    float s = 0.0f;
#pragma unroll
    for (int k = 0; k < 6; ++k) {             // q = q0 + 4k  (0..23)
        float4 v = r4[q0 + 4 * k];
        float4 ww = w4s[q0 + 4 * k];
        s += v.x * ww.x + v.y * ww.y + v.z * ww.z + v.w * ww.w;
    }
    if (q0 == 0) {                            // tail q = 24
        float4 v = r4[24];
        float4 ww = w4s[24];
        s += v.x * ww.x + v.y * ww.y + v.z * ww.z + v.w * ww.w;
    }
    // reduce across the 4-lane quarter group
    s += __shfl_xor(s, 1, 64);
    s += __shfl_xor(s, 2, 64);
    if (q0 == 0) out[row] = s;
}

extern "C" void kernel_launch(void* const* d_in, const int* in_sizes, int n_in,
                              void* d_out, int out_size, void* d_ws, size_t ws_size,
                              hipStream_t stream) {
    const float* A = (const float*)d_in[0];
    float* out = (float*)d_out;
    const int d = in_sizes[0] / NCLI;

    float* G = (float*)d_ws;           // 100*100 f32 (upper triangle used)
    float* w = G + NCLI * NCLI;        // 100 f32 weights

    const int n4 = (NCLI * NCLI) / 4;  // 2500 float4
    zero_kernel<<<(n4 + 255) / 256, 256, 0, stream>>>((float4*)G, n4);

    const int nchunks = (d + DK - 1) / DK;
    const int gblocks = nchunks < GBLK ? nchunks : GBLK;
    gram_mfma<<<gblocks, 256, 0, stream>>>(A, G, (long)d, nchunks);

    weights_kernel<<<1, 128, 0, stream>>>(G, w);

    const int oblocks = (d + 63) / 64;  // 64 rows per block
    out_kernel<<<oblocks, 256, 0, stream>>>(A, w, out, d, oblocks);
}